// Round 3
// baseline (408.425 us; speedup 1.0000x reference)
//
#include <hip/hip_runtime.h>

// _UnitDiscreteActionHead: out[b][n] (B x 6, f32) from
//   logits (24x24 f32), mask (B x 24 x 24 bool), conv (24x24 int32 in [0,6)).
// GEMM formulation: out16 = mask(B x 576) * W(576 x 16), W cols (bf16):
//   0..5: (conv==n)?bf16(logit):0   6..11: (conv==n-6)?1:0   12: 1   13..15: 0
// mfma_f32_16x16x32_bf16. Mask dtype (u8 vs int32) auto-detected on device;
// each path uses a W table whose k-order matches its A-fragment pack order.

typedef short bf16x8 __attribute__((ext_vector_type(8)));
typedef float f32x4 __attribute__((ext_vector_type(4)));

union U4S8 { uint4 u; bf16x8 s; };

__device__ inline unsigned short f2bf(float f) {
  unsigned u = __builtin_bit_cast(unsigned, f);
  u += 0x7FFFu + ((u >> 16) & 1u);   // RNE
  return (unsigned short)(u >> 16);
}

// flag=1 iff mask looks like int32 bools (first 256 dwords all <= 1).
__global__ void detect_kernel(const unsigned* __restrict__ mask_dw,
                              int* __restrict__ flag) {
  __shared__ int ok;
  if (threadIdx.x == 0) ok = 1;
  __syncthreads();
  if (mask_dw[threadIdx.x] > 1u) ok = 0;   // benign race, same value
  __syncthreads();
  if (threadIdx.x == 0) *flag = ok;
}

// One thread per (n, cell). wt_id: k == cell. wt_perm: k-order matching the
// u8 byte-pair pack (hw-k = kt*64+sub*32+q*8+j <-> cell = kt*64+q*16+sub*8+p(j),
// p = {0,2,1,3,4,6,5,7}, an involution).
__global__ void build_wt_kernel(const float* __restrict__ logits,
                                const int* __restrict__ conv,
                                unsigned short* __restrict__ wt_perm,
                                unsigned short* __restrict__ wt_id) {
  int idx = blockIdx.x * blockDim.x + threadIdx.x;
  if (idx >= 16 * 576) return;
  int n = idx / 576;
  int cell = idx - n * 576;
  int g = conv[cell];
  unsigned short v = 0;
  if (n < 6)        v = (g == n)       ? f2bf(logits[cell]) : (unsigned short)0;
  else if (n < 12)  v = (g == (n - 6)) ? (unsigned short)0x3F80 : (unsigned short)0;
  else if (n == 12) v = 0x3F80;
  wt_id[n * 576 + cell] = v;
  int jp = cell & 7, q = (cell >> 4) & 3, sub = (cell >> 3) & 1, kt = cell >> 6;
  int j = (jp & 4) | ((jp & 1) << 1) | ((jp & 2) >> 1);
  wt_perm[n * 576 + kt * 64 + sub * 32 + q * 8 + j] = v;
}

// Two bf16 cells from one dword of mask bytes (LSB of each byte).
__device__ inline void cvt_pair(unsigned x, unsigned& lo, unsigned& hi) {
  lo = (x & 0x00010001u) * 0x3F80u;          // bf16(b0) | bf16(b2)<<16
  hi = ((x >> 8) & 0x00010001u) * 0x3F80u;   // bf16(b1) | bf16(b3)<<16
}

__global__ __launch_bounds__(256) void head_kernel(
    const unsigned char* __restrict__ mask,
    const unsigned short* __restrict__ wt_perm,
    const unsigned short* __restrict__ wt_id,
    const int* __restrict__ flag,
    float* __restrict__ out,
    int ntiles) {
  int gid  = blockIdx.x * blockDim.x + threadIdx.x;
  int wave = gid >> 6;
  int lane = threadIdx.x & 63;
  if (wave >= ntiles) return;

  int m = lane & 15;        // A: batch row within tile; B: output column n
  int q = lane >> 4;        // quad
  size_t tb = (size_t)wave * 16;

  f32x4 acc = {0.f, 0.f, 0.f, 0.f};

  if (*flag) {
    // ---- mask stored as int32 (one bool per dword), identity k-order ----
    const unsigned* mp = (const unsigned*)mask + (tb + (size_t)m) * 576 + q * 8;
    const unsigned char* bp = (const unsigned char*)wt_id + m * 1152 + q * 16;
#pragma unroll 3
    for (int kt = 0; kt < 18; ++kt) {
      uint4 u = *(const uint4*)(mp + kt * 32);       // cells k..k+3 (k=kt*32+q*8)
      uint4 w = *(const uint4*)(mp + kt * 32 + 4);   // cells k+4..k+7
      U4S8 a, b;
      b.u = *(const uint4*)(bp + kt * 64);
      a.u = make_uint4((u.x | (u.y << 16)) * 0x3F80u,
                       (u.z | (u.w << 16)) * 0x3F80u,
                       (w.x | (w.y << 16)) * 0x3F80u,
                       (w.z | (w.w << 16)) * 0x3F80u);
      acc = __builtin_amdgcn_mfma_f32_16x16x32_bf16(a.s, b.s, acc, 0, 0, 0);
    }
  } else {
    // ---- mask stored as u8 bools, byte-pair-permuted k-order ----
    const unsigned char* ap = mask + (tb + (size_t)m) * 576 + q * 16;
    const unsigned char* bp = (const unsigned char*)wt_perm + m * 1152 + q * 16;
#pragma unroll 3
    for (int kt = 0; kt < 9; ++kt) {
      uint4 av = *(const uint4*)(ap + kt * 64);     // 16 cells
      U4S8 a0, a1, b0, b1;
      b0.u = *(const uint4*)(bp + kt * 128);
      b1.u = *(const uint4*)(bp + kt * 128 + 64);
      unsigned l0, h0, l1, h1;
      cvt_pair(av.x, l0, h0); cvt_pair(av.y, l1, h1);
      a0.u = make_uint4(l0, h0, l1, h1);
      cvt_pair(av.z, l0, h0); cvt_pair(av.w, l1, h1);
      a1.u = make_uint4(l0, h0, l1, h1);
      acc = __builtin_amdgcn_mfma_f32_16x16x32_bf16(a0.s, b0.s, acc, 0, 0, 0);
      acc = __builtin_amdgcn_mfma_f32_16x16x32_bf16(a1.s, b1.s, acc, 0, 0, 0);
    }
  }

  // Epilogue. C/D layout: col(n) = lane&15, row(batch) = q*4 + r.
  int col = m;
  int srcCnt = (lane & 48) + ((col < 6) ? (col + 6) : 0);
  int srcTot = (lane & 48) + 12;
  float scale = (col == 5) ? (1.0f / 225.0f) : 1.0f;
  const float FMIN = -3.4028234663852886e38f;

#pragma unroll
  for (int r = 0; r < 4; ++r) {
    float s   = acc[r];
    float cnt = __shfl(s, srcCnt);
    float tot = __shfl(s, srcTot);
    if (col < 6) {
      float o;
      if (tot < 0.5f)       o = (col == 0) ? 1.0f : FMIN;
      else if (cnt > 0.5f)  o = s * scale;
      else                  o = FMIN;
      size_t b = tb + (size_t)q * 4 + r;
      out[b * 6 + col] = o;
    }
  }
}

extern "C" void kernel_launch(void* const* d_in, const int* in_sizes, int n_in,
                              void* d_out, int out_size, void* d_ws, size_t ws_size,
                              hipStream_t stream) {
  const float*          logits = (const float*)d_in[0];
  const unsigned char*  mask   = (const unsigned char*)d_in[1];
  const int*            conv   = (const int*)d_in[2];
  float*                out    = (float*)d_out;

  int*            flag    = (int*)d_ws;
  unsigned short* wt_perm = (unsigned short*)((char*)d_ws + 64);
  unsigned short* wt_id   = wt_perm + 16 * 576;     // +18432 B (64-aligned)

  int B = in_sizes[1] / 576;       // 131072
  int ntiles = B / 16;             // 8192

  detect_kernel<<<1, 256, 0, stream>>>((const unsigned*)mask, flag);
  build_wt_kernel<<<36, 256, 0, stream>>>(logits, conv, wt_perm, wt_id);

  int threads = ntiles * 64;       // one wave per 16-batch tile
  head_kernel<<<(threads + 255) / 256, 256, 0, stream>>>(
      mask, wt_perm, wt_id, flag, out, ntiles);
}

// Round 5
// 395.631 us; speedup vs baseline: 1.0323x; 1.0323x over previous
//
#include <hip/hip_runtime.h>

// _UnitDiscreteActionHead: out[b][n] (B x 6, f32) from
//   logits (24x24 f32), mask (B x 24 x 24 bool), conv (24x24 int32 in [0,6)).
// GEMM formulation: out16 = mask(B x 576) * W(576 x 16), W cols (bf16):
//   0..5: (conv==n)?bf16(logit):0   6..11: (conv==n-6)?1:0   12: 1   13..15: 0
// mfma_f32_16x16x32_bf16. Mask dtype (u8 vs int32) auto-detected on device;
// each path uses a W table whose k-order matches its A-fragment pack order.
// R5: fix nontemporal loads (need clang ext_vector pointee, not HIP uint4).

typedef short bf16x8 __attribute__((ext_vector_type(8)));
typedef float f32x4 __attribute__((ext_vector_type(4)));
typedef unsigned uint4n __attribute__((ext_vector_type(4)));  // nt-load-able

union U4S8 { uint4n u; bf16x8 s; };

__device__ inline unsigned short f2bf(float f) {
  unsigned u = __builtin_bit_cast(unsigned, f);
  u += 0x7FFFu + ((u >> 16) & 1u);   // RNE
  return (unsigned short)(u >> 16);
}

// One thread per (n, cell), 36 blocks x 256. Block 0 additionally detects the
// mask dtype: int32 bools -> first 256 dwords all <= 1; u8 bools -> random
// 0/1 bytes make a dword > 1 with overwhelming probability.
// wt_id: k == cell. wt_perm: k-order matching the u8 byte-pair pack
// (hw-k = kt*64+sub*32+q*8+j <-> cell = kt*64+q*16+sub*8+p(j),
//  p = {0,2,1,3,4,6,5,7}, an involution).
__global__ void build_wt_kernel(const float* __restrict__ logits,
                                const int* __restrict__ conv,
                                const unsigned* __restrict__ mask_dw,
                                unsigned short* __restrict__ wt_perm,
                                unsigned short* __restrict__ wt_id,
                                int* __restrict__ flag) {
  if (blockIdx.x == 0) {
    unsigned long long bad = __ballot(mask_dw[threadIdx.x] > 1u);
    __shared__ int votes[4];
    if ((threadIdx.x & 63) == 0) votes[threadIdx.x >> 6] = (bad != 0ull);
    __syncthreads();
    if (threadIdx.x == 0)
      *flag = !(votes[0] | votes[1] | votes[2] | votes[3]);
  }
  int idx = blockIdx.x * blockDim.x + threadIdx.x;
  if (idx >= 16 * 576) return;
  int n = idx / 576;
  int cell = idx - n * 576;
  int g = conv[cell];
  unsigned short v = 0;
  if (n < 6)        v = (g == n)       ? f2bf(logits[cell]) : (unsigned short)0;
  else if (n < 12)  v = (g == (n - 6)) ? (unsigned short)0x3F80 : (unsigned short)0;
  else if (n == 12) v = 0x3F80;
  wt_id[n * 576 + cell] = v;
  int jp = cell & 7, q = (cell >> 4) & 3, sub = (cell >> 3) & 1, kt = cell >> 6;
  int j = (jp & 4) | ((jp & 1) << 1) | ((jp & 2) >> 1);
  wt_perm[n * 576 + kt * 64 + sub * 32 + q * 8 + j] = v;
}

// Two bf16 cells from one dword of mask bytes (LSB of each byte).
__device__ inline void cvt_pair(unsigned x, unsigned& lo, unsigned& hi) {
  lo = (x & 0x00010001u) * 0x3F80u;          // bf16(b0) | bf16(b2)<<16
  hi = ((x >> 8) & 0x00010001u) * 0x3F80u;   // bf16(b1) | bf16(b3)<<16
}

__global__ __launch_bounds__(256) void head_kernel(
    const unsigned char* __restrict__ mask,
    const unsigned short* __restrict__ wt_perm,
    const unsigned short* __restrict__ wt_id,
    const int* __restrict__ flag,
    float* __restrict__ out,
    int ntiles) {
  int gid  = blockIdx.x * blockDim.x + threadIdx.x;
  int wave = gid >> 6;
  int lane = threadIdx.x & 63;
  if (wave >= ntiles) return;

  int m = lane & 15;        // A: batch row within tile; B: output column n
  int q = lane >> 4;        // quad
  size_t tb = (size_t)wave * 16;

  f32x4 acc = {0.f, 0.f, 0.f, 0.f};

  if (*flag) {
    // ---- mask stored as int32 (one bool per dword), identity k-order ----
    const unsigned* mp = (const unsigned*)mask + (tb + (size_t)m) * 576 + q * 8;
    const unsigned char* bp = (const unsigned char*)wt_id + m * 1152 + q * 16;
#pragma unroll 3
    for (int kt = 0; kt < 18; ++kt) {
      uint4n u = __builtin_nontemporal_load((const uint4n*)(mp + kt * 32));
      uint4n w = __builtin_nontemporal_load((const uint4n*)(mp + kt * 32 + 4));
      U4S8 a, b;
      b.u = *(const uint4n*)(bp + kt * 64);
      a.u = (uint4n){(u.x | (u.y << 16)) * 0x3F80u,
                     (u.z | (u.w << 16)) * 0x3F80u,
                     (w.x | (w.y << 16)) * 0x3F80u,
                     (w.z | (w.w << 16)) * 0x3F80u};
      acc = __builtin_amdgcn_mfma_f32_16x16x32_bf16(a.s, b.s, acc, 0, 0, 0);
    }
  } else {
    // ---- mask stored as u8 bools, byte-pair-permuted k-order ----
    const unsigned char* ap = mask + (tb + (size_t)m) * 576 + q * 16;
    const unsigned char* bp = (const unsigned char*)wt_perm + m * 1152 + q * 16;
#pragma unroll 3
    for (int kt = 0; kt < 9; ++kt) {
      uint4n av = __builtin_nontemporal_load((const uint4n*)(ap + kt * 64));
      U4S8 a0, a1, b0, b1;
      b0.u = *(const uint4n*)(bp + kt * 128);
      b1.u = *(const uint4n*)(bp + kt * 128 + 64);
      unsigned l0, h0, l1, h1;
      cvt_pair(av.x, l0, h0); cvt_pair(av.y, l1, h1);
      a0.u = (uint4n){l0, h0, l1, h1};
      cvt_pair(av.z, l0, h0); cvt_pair(av.w, l1, h1);
      a1.u = (uint4n){l0, h0, l1, h1};
      acc = __builtin_amdgcn_mfma_f32_16x16x32_bf16(a0.s, b0.s, acc, 0, 0, 0);
      acc = __builtin_amdgcn_mfma_f32_16x16x32_bf16(a1.s, b1.s, acc, 0, 0, 0);
    }
  }

  // Epilogue. C/D layout: col(n) = lane&15, row(batch) = q*4 + r.
  int col = m;
  int srcCnt = (lane & 48) + ((col < 6) ? (col + 6) : 0);
  int srcTot = (lane & 48) + 12;
  float scale = (col == 5) ? (1.0f / 225.0f) : 1.0f;
  const float FMIN = -3.4028234663852886e38f;

#pragma unroll
  for (int r = 0; r < 4; ++r) {
    float s   = acc[r];
    float cnt = __shfl(s, srcCnt);
    float tot = __shfl(s, srcTot);
    if (col < 6) {
      float o;
      if (tot < 0.5f)       o = (col == 0) ? 1.0f : FMIN;
      else if (cnt > 0.5f)  o = s * scale;
      else                  o = FMIN;
      size_t b = tb + (size_t)q * 4 + r;
      out[b * 6 + col] = o;
    }
  }
}

extern "C" void kernel_launch(void* const* d_in, const int* in_sizes, int n_in,
                              void* d_out, int out_size, void* d_ws, size_t ws_size,
                              hipStream_t stream) {
  const float*          logits = (const float*)d_in[0];
  const unsigned char*  mask   = (const unsigned char*)d_in[1];
  const int*            conv   = (const int*)d_in[2];
  float*                out    = (float*)d_out;

  int*            flag    = (int*)d_ws;
  unsigned short* wt_perm = (unsigned short*)((char*)d_ws + 64);
  unsigned short* wt_id   = wt_perm + 16 * 576;     // +18432 B (64-aligned)

  int B = in_sizes[1] / 576;       // 131072
  int ntiles = B / 16;             // 8192

  build_wt_kernel<<<36, 256, 0, stream>>>(logits, conv, (const unsigned*)mask,
                                          wt_perm, wt_id, flag);

  int threads = ntiles * 64;       // one wave per 16-batch tile
  head_kernel<<<(threads + 255) / 256, 256, 0, stream>>>(
      mask, wt_perm, wt_id, flag, out, ntiles);
}